// Round 1
// baseline (16207.068 us; speedup 1.0000x reference)
//
#include <hip/hip_runtime.h>
#include <math.h>

#define VOL 110592   // 48*48*48
#define CINP 64      // input channels
#define PCH 64       // proj channels
#define NOC 128      // out channels
#define NK  343      // 7^3 offsets

// ---------------------------------------------------------------------------
// 1x1x1 conv (64x64 matvec) + bias + channel L2-normalize.
// Output voxel-major: out[v][64] so the correlation kernel gets contiguous rows.
__global__ __launch_bounds__(256) void proj_l2norm_kernel(
    const float* __restrict__ x,   // [64][VOL]
    const float* __restrict__ w,   // [64][64]
    const float* __restrict__ b,   // [64]
    float* __restrict__ out)       // [VOL][64]
{
    const int v = blockIdx.x * 256 + threadIdx.x;
    float xr[CINP];
    for (int ci = 0; ci < CINP; ci++)
        xr[ci] = x[(size_t)ci * VOL + v];           // coalesced across lanes

    float acc[PCH];
    for (int c = 0; c < PCH; c++) {
        float a = b[c];
        #pragma unroll
        for (int ci = 0; ci < CINP; ci++)
            a = fmaf(w[c * CINP + ci], xr[ci], a);  // uniform -> scalar loads
        acc[c] = a;
    }
    float s = 0.f;
    #pragma unroll
    for (int c = 0; c < PCH; c++) s += acc[c] * acc[c];
    const float inv = 1.0f / fmaxf(sqrtf(s), 1e-12f);
    #pragma unroll
    for (int c = 0; c < PCH; c++)
        out[(size_t)v * PCH + c] = acc[c] * inv;
}

// ---------------------------------------------------------------------------
// Correlation over 343 offsets with edge-clamped neighbor + fused softmax
// expected-offset. Writes feat channels [0..342]=corr, [343..345]=eo.
// corr values are dots of unit vectors -> |corr|<=1, so softmax needs no
// max-subtraction (exp in [0.37, 2.72]).
__global__ __launch_bounds__(256) void corr_softmax_kernel(
    const float* __restrict__ sp,   // [VOL][64]
    const float* __restrict__ tp,   // [VOL][64]
    float* __restrict__ feat)       // [346][VOL]
{
    const int v = blockIdx.x * 256 + threadIdx.x;
    const int x = v % 48, y = (v / 48) % 48, z = v / 2304;

    float4 sr[16];
    const float4* sp4 = (const float4*)(sp + (size_t)v * PCH);
    #pragma unroll
    for (int i = 0; i < 16; i++) sr[i] = sp4[i];

    float ssum = 0.f, e0 = 0.f, e1 = 0.f, e2 = 0.f;
    for (int dz = -3; dz <= 3; dz++) {
        const int zc = min(max(z + dz, 0), 47);
        for (int dy = -3; dy <= 3; dy++) {
            const int yc = min(max(y + dy, 0), 47);
            const int rowbase = (zc * 48 + yc) * 48;
            for (int dx = -3; dx <= 3; dx++) {
                const int xc = min(max(x + dx, 0), 47);
                const float4* tr = (const float4*)(tp + (size_t)(rowbase + xc) * PCH);
                float dot = 0.f;
                #pragma unroll
                for (int i = 0; i < 16; i++) {
                    const float4 t4 = tr[i];
                    dot = fmaf(sr[i].x, t4.x,
                          fmaf(sr[i].y, t4.y,
                          fmaf(sr[i].z, t4.z,
                          fmaf(sr[i].w, t4.w, dot))));
                }
                const int k = (dz + 3) * 49 + (dy + 3) * 7 + (dx + 3);
                feat[(size_t)k * VOL + v] = dot;
                const float e = __expf(dot);
                ssum += e;
                e0 += e * (float)dz;
                e1 += e * (float)dy;
                e2 += e * (float)dx;
            }
        }
    }
    const float inv = 1.f / ssum;
    feat[(size_t)343 * VOL + v] = e0 * inv;
    feat[(size_t)344 * VOL + v] = e1 * inv;
    feat[(size_t)345 * VOL + v] = e2 * inv;
}

// ---------------------------------------------------------------------------
// Direct 3x3x3 conv, zero padding. Tile: 4(z) x 4(y) x 16(x) voxels, one
// thread per voxel, 32 output channels per thread (acc[32]).
// grid = (432 tiles, 4 oc-groups). Per ic: stage 6x6x18 window in LDS,
// preload 27 taps into regs, 27*32 FMA with scalar-loaded weights.
template<int CIN_T>
__global__ __launch_bounds__(256) void conv3_kernel(
    const float* __restrict__ in,    // [CIN_T][VOL]
    const float* __restrict__ w,     // [128][CIN_T][27]
    const float* __restrict__ bias,  // [128]
    float* __restrict__ out)         // [128][VOL]
{
    const int tile = blockIdx.x;                 // 432 = 3(x) * 12(y) * 12(z)
    const int oc0  = blockIdx.y * 32;
    const int tx = tile % 3, ty = (tile / 3) % 12, tz = tile / 36;
    const int x0 = tx * 16, y0 = ty * 4, z0 = tz * 4;
    const int t  = threadIdx.x;
    const int lx = t & 15, ly = (t >> 4) & 3, lz = t >> 6;

    __shared__ float win[6 * 6 * 18];

    float acc[32];
    #pragma unroll
    for (int oc = 0; oc < 32; oc++) acc[oc] = bias[oc0 + oc];

    for (int ic = 0; ic < CIN_T; ic++) {
        __syncthreads();   // protect win reads of previous iteration
        for (int i = t; i < 648; i += 256) {
            const int wx = i % 18, wy = (i / 18) % 6, wz = i / 108;
            const int gx = x0 + wx - 1, gy = y0 + wy - 1, gz = z0 + wz - 1;
            float vv = 0.f;
            if (((unsigned)gx < 48u) && ((unsigned)gy < 48u) && ((unsigned)gz < 48u))
                vv = in[(size_t)ic * VOL + (gz * 48 + gy) * 48 + gx];
            win[i] = vv;
        }
        __syncthreads();

        float xin[27];
        #pragma unroll
        for (int dz = 0; dz < 3; dz++)
        #pragma unroll
        for (int dy = 0; dy < 3; dy++)
        #pragma unroll
        for (int dx = 0; dx < 3; dx++)
            xin[(dz * 3 + dy) * 3 + dx] = win[(lz + dz) * 108 + (ly + dy) * 18 + (lx + dx)];

        const float* wp = w + ((size_t)oc0 * CIN_T + ic) * 27;
        #pragma unroll
        for (int oc = 0; oc < 32; oc++) {
            const float* wo = wp + (size_t)oc * CIN_T * 27;  // 27 contiguous
            #pragma unroll
            for (int tap = 0; tap < 27; tap++)
                acc[oc] = fmaf(wo[tap], xin[tap], acc[oc]);
        }
    }

    const int v = ((z0 + lz) * 48 + (y0 + ly)) * 48 + (x0 + lx);
    #pragma unroll
    for (int oc = 0; oc < 32; oc++)
        out[(size_t)(oc0 + oc) * VOL + v] = acc[oc];
}

// ---------------------------------------------------------------------------
// Per-channel mean / rstd over the full volume (biased var, eps inside rsqrt).
__global__ __launch_bounds__(256) void chan_stats_kernel(
    const float* __restrict__ x, float* __restrict__ stats /* [128][2] */)
{
    const int c = blockIdx.x;
    const float* p = x + (size_t)c * VOL;
    float s = 0.f, s2 = 0.f;
    for (int i = threadIdx.x; i < VOL; i += 256) {
        const float v = p[i];
        s += v;
        s2 = fmaf(v, v, s2);
    }
    __shared__ float rs[256], rs2[256];
    rs[threadIdx.x] = s; rs2[threadIdx.x] = s2;
    __syncthreads();
    for (int off = 128; off > 0; off >>= 1) {
        if (threadIdx.x < off) {
            rs[threadIdx.x]  += rs[threadIdx.x + off];
            rs2[threadIdx.x] += rs2[threadIdx.x + off];
        }
        __syncthreads();
    }
    if (threadIdx.x == 0) {
        const float mean = rs[0] / (float)VOL;
        const float var  = rs2[0] / (float)VOL - mean * mean;
        stats[c * 2]     = mean;
        stats[c * 2 + 1] = rsqrtf(var + 1e-5f);
    }
}

__device__ __forceinline__ float gelu_exact(float h)
{
    return 0.5f * h * (1.f + erff(h * 0.70710678118654752f));
}

// Elementwise instance-norm apply + exact GELU. float4, grid covers 128*VOL.
__global__ __launch_bounds__(256) void norm_gelu_kernel(
    const float* __restrict__ x, const float* __restrict__ stats,
    float* __restrict__ out)
{
    const size_t i = (size_t)blockIdx.x * 256 + threadIdx.x;  // float4 index
    const int c = (int)(i / (VOL / 4));                       // VOL%4==0
    const float mean = stats[c * 2], rstd = stats[c * 2 + 1];
    const float4 xv = ((const float4*)x)[i];
    float4 o;
    o.x = gelu_exact((xv.x - mean) * rstd);
    o.y = gelu_exact((xv.y - mean) * rstd);
    o.z = gelu_exact((xv.z - mean) * rstd);
    o.w = gelu_exact((xv.w - mean) * rstd);
    ((float4*)out)[i] = o;
}

// ---------------------------------------------------------------------------
extern "C" void kernel_launch(void* const* d_in, const int* in_sizes, int n_in,
                              void* d_out, int out_size, void* d_ws, size_t ws_size,
                              hipStream_t stream)
{
    const float* src = (const float*)d_in[0];
    const float* tgt = (const float*)d_in[1];
    const float* psw = (const float*)d_in[2];
    const float* psb = (const float*)d_in[3];
    const float* ptw = (const float*)d_in[4];
    const float* ptb = (const float*)d_in[5];
    const float* e1w = (const float*)d_in[6];
    const float* e1b = (const float*)d_in[7];
    const float* e2w = (const float*)d_in[8];
    const float* e2b = (const float*)d_in[9];

    float* ws = (float*)d_ws;
    // Workspace layout (floats). Lifetimes allow overlap:
    //   [0, 64*VOL)          sp        (dead after corr)  ->  h1 reuses [0,128*VOL)
    //   [64*VOL, 128*VOL)    tp        (dead after corr)
    //   [128*VOL, 474*VOL)   feat[346] (dead after conv1) ->  h2 reuses its head
    //   [474*VOL, +256)      stats
    // Total ~210 MB.
    float* sp    = ws;
    float* tp    = ws + (size_t)64 * VOL;
    float* feat  = ws + (size_t)128 * VOL;
    float* h1    = ws;                       // overlaps sp+tp (exactly 128*VOL)
    float* h2    = feat;                     // overlaps feat head
    float* stats = ws + (size_t)474 * VOL;

    proj_l2norm_kernel<<<432, 256, 0, stream>>>(src, psw, psb, sp);
    proj_l2norm_kernel<<<432, 256, 0, stream>>>(tgt, ptw, ptb, tp);
    corr_softmax_kernel<<<432, 256, 0, stream>>>(sp, tp, feat);

    conv3_kernel<346><<<dim3(432, 4), 256, 0, stream>>>(feat, e1w, e1b, h1);
    chan_stats_kernel<<<128, 256, 0, stream>>>(h1, stats);
    norm_gelu_kernel<<<(NOC * VOL) / 1024, 256, 0, stream>>>(h1, stats, h1);

    conv3_kernel<128><<<dim3(432, 4), 256, 0, stream>>>(h1, e2w, e2b, h2);
    chan_stats_kernel<<<128, 256, 0, stream>>>(h2, stats);
    norm_gelu_kernel<<<(NOC * VOL) / 1024, 256, 0, stream>>>(h2, stats, (float*)d_out);
}

// Round 2
// 2782.779 us; speedup vs baseline: 5.8241x; 5.8241x over previous
//
#include <hip/hip_runtime.h>
#include <math.h>
#include <stdint.h>

#define VOL 110592   // 48*48*48
#define CINP 64      // input channels
#define PCH 64       // proj channels

typedef short short8 __attribute__((ext_vector_type(8)));
typedef float floatx4 __attribute__((ext_vector_type(4)));

__device__ __forceinline__ ushort f2bf(float f) {
    union { float f; uint32_t u; } v; v.f = f;
    uint32_t r = v.u + 0x7FFFu + ((v.u >> 16) & 1u);   // RNE
    return (ushort)(r >> 16);
}

// ---------------------------------------------------------------------------
// 1x1x1 conv (64x64 matvec) + bias + channel L2-normalize. Voxel-major output.
__global__ __launch_bounds__(256) void proj_l2norm_kernel(
    const float* __restrict__ x,   // [64][VOL]
    const float* __restrict__ w,   // [64][64]
    const float* __restrict__ b,   // [64]
    float* __restrict__ out)       // [VOL][64]
{
    const int v = blockIdx.x * 256 + threadIdx.x;
    float xr[CINP];
    for (int ci = 0; ci < CINP; ci++)
        xr[ci] = x[(size_t)ci * VOL + v];

    float acc[PCH];
    for (int c = 0; c < PCH; c++) {
        float a = b[c];
        #pragma unroll
        for (int ci = 0; ci < CINP; ci++)
            a = fmaf(w[c * CINP + ci], xr[ci], a);
        acc[c] = a;
    }
    float s = 0.f;
    #pragma unroll
    for (int c = 0; c < PCH; c++) s += acc[c] * acc[c];
    const float inv = 1.0f / fmaxf(sqrtf(s), 1e-12f);
    #pragma unroll
    for (int c = 0; c < PCH; c++)
        out[(size_t)v * PCH + c] = acc[c] * inv;
}

// ---------------------------------------------------------------------------
// Correlation (343 offsets, edge-clamped) + fused softmax expected-offset.
// Writes featT[v][352] in bf16: k=0..342 corr, 343..345 eo, 346..351 zero pad.
// |corr|<=1 (unit vectors) so softmax needs no max-subtraction.
__global__ __launch_bounds__(256) void corr_softmax_kernel(
    const float* __restrict__ sp,   // [VOL][64]
    const float* __restrict__ tp,   // [VOL][64]
    ushort* __restrict__ featT)     // [VOL][352] bf16
{
    const int v = blockIdx.x * 256 + threadIdx.x;
    const int x = v % 48, y = (v / 48) % 48, z = v / 2304;

    float4 sr[16];
    const float4* sp4 = (const float4*)(sp + (size_t)v * PCH);
    #pragma unroll
    for (int i = 0; i < 16; i++) sr[i] = sp4[i];

    ushort* op = featT + (size_t)v * 352;

    float ssum = 0.f, e0 = 0.f, e1 = 0.f, e2 = 0.f;
    int k = 0;
    for (int dz = -3; dz <= 3; dz++) {
        const int zc = min(max(z + dz, 0), 47);
        for (int dy = -3; dy <= 3; dy++) {
            const int yc = min(max(y + dy, 0), 47);
            const int rowbase = (zc * 48 + yc) * 48;
            for (int dx = -3; dx <= 3; dx++) {
                const int xc = min(max(x + dx, 0), 47);
                const float4* tr = (const float4*)(tp + (size_t)(rowbase + xc) * PCH);
                float dot = 0.f;
                #pragma unroll
                for (int i = 0; i < 16; i++) {
                    const float4 t4 = tr[i];
                    dot = fmaf(sr[i].x, t4.x,
                          fmaf(sr[i].y, t4.y,
                          fmaf(sr[i].z, t4.z,
                          fmaf(sr[i].w, t4.w, dot))));
                }
                op[k++] = f2bf(dot);
                const float e = __expf(dot);
                ssum += e;
                e0 += e * (float)dz;
                e1 += e * (float)dy;
                e2 += e * (float)dx;
            }
        }
    }
    const float inv = 1.f / ssum;
    op[343] = f2bf(e0 * inv);
    op[344] = f2bf(e1 * inv);
    op[345] = f2bf(e2 * inv);
    #pragma unroll
    for (int j = 346; j < 352; j++) op[j] = 0;
}

// ---------------------------------------------------------------------------
// Weight pre-transpose: w[128][CIN][27] fp32 -> wT[27][128][CPAD] bf16 (pad 0).
template<int CIN, int CPAD>
__global__ __launch_bounds__(256) void wprep_kernel(
    const float* __restrict__ w, ushort* __restrict__ wTo)
{
    const int oc = blockIdx.x;
    for (int idx = threadIdx.x; idx < CPAD * 27; idx += 256) {
        const int icp = idx / 27, tap = idx - icp * 27;
        float val = 0.f;
        if (icp < CIN) val = w[((size_t)oc * CIN + icp) * 27 + tap];
        wTo[((size_t)tap * 128 + oc) * CPAD + icp] = f2bf(val);
    }
}

// ---------------------------------------------------------------------------
// Implicit-GEMM 3x3x3 conv via bf16 MFMA (zero padding).
// Block: 128 voxels (2z x 4y x 16x) x 128 oc. 4 waves: wave&1 -> oc half,
// wave>>1 -> voxel half. Wave computes 4 oc-subtiles x 4 voxel-subtiles.
// K-loop: ic-chunks of 32 (window staged in LDS as [pos][ic32], 80B/pos) x
// 27 taps. A-operand = weights wT[tap][oc][CPAD] (global 16B loads, L2-hot);
// B-operand = input window (ds_read_b128).
// MFMA layouts (m89/m91-verified): Aop[i=lane&15][k=q*8+j],
// Bop[k=q*8+j][n=lane&15], D reg r = D[i=q*4+r][n=lane&15].
template<int CPAD>
__global__ __launch_bounds__(256) void conv3_mfma_kernel(
    const ushort* __restrict__ xT,   // [VOL][CPAD] bf16
    const ushort* __restrict__ wT,   // [27][128][CPAD] bf16
    const float* __restrict__ bias,  // [128]
    float* __restrict__ out)         // [128][VOL] fp32
{
    const int blk = blockIdx.x;                 // 864 = 3(tx) * 12(ty) * 24(tz)
    const int tx = blk % 3, ty = (blk / 3) % 12, tz = blk / 36;
    const int x0 = tx * 16, y0 = ty * 4, z0 = tz * 2;
    const int t = threadIdx.x;
    const int wave = t >> 6;
    const int lane = t & 63;
    const int l = lane & 15;
    const int q = lane >> 4;
    const int ocw = (wave & 1) * 64;            // wave's oc base
    const int mzw = wave >> 1;                  // wave's local z (voxel half)

    // window: 4(z) x 6(y) x 18(x) = 432 pos, 32 ic bf16 each, padded to 80B
    __shared__ __align__(16) ushort win[432 * 40];

    floatx4 acc[4][4];
    #pragma unroll
    for (int i = 0; i < 4; i++)
        #pragma unroll
        for (int j = 0; j < 4; j++)
            acc[i][j] = (floatx4){0.f, 0.f, 0.f, 0.f};

    const int NCH = CPAD / 32;
    for (int ck = 0; ck < NCH; ck++) {
        __syncthreads();
        // stage: 432 pos x 4 granules(16B) = 1728 tasks over 256 threads
        #pragma unroll
        for (int it = 0; it < 7; it++) {
            const int i = t + it * 256;
            if (i < 1728) {
                const int p = i >> 2, g = i & 3;
                const int wz = p / 108, pr = p - wz * 108;
                const int wy = pr / 18, wx = pr - wy * 18;
                const int gz = z0 + wz - 1, gy = y0 + wy - 1, gx = x0 + wx - 1;
                int4 val = {0, 0, 0, 0};
                if ((unsigned)gx < 48u && (unsigned)gy < 48u && (unsigned)gz < 48u) {
                    const size_t gv = (size_t)((gz * 2304) + gy * 48 + gx);
                    val = *(const int4*)(xT + gv * CPAD + ck * 32 + g * 8);
                }
                *(int4*)(&win[p * 40 + g * 8]) = val;
            }
        }
        __syncthreads();

        const ushort* wp0 = wT + (size_t)(ocw + l) * CPAD + ck * 32 + q * 8;
        for (int tap = 0; tap < 27; tap++) {
            const int dz = tap / 9, rr = tap - dz * 9;
            const int dy = rr / 3, dx = rr - dy * 3;
            const ushort* wp = wp0 + (size_t)tap * (128 * CPAD);
            const short8 a0 = *(const short8*)(wp);
            const short8 a1 = *(const short8*)(wp + 16 * CPAD);
            const short8 a2 = *(const short8*)(wp + 32 * CPAD);
            const short8 a3 = *(const short8*)(wp + 48 * CPAD);
            const int pb = ((mzw + dz) * 108 + dy * 18 + l + dx) * 40 + q * 8;
            #pragma unroll
            for (int mt = 0; mt < 4; mt++) {
                const short8 b = *(const short8*)(&win[pb + mt * 720]);
                acc[0][mt] = __builtin_amdgcn_mfma_f32_16x16x32_bf16(a0, b, acc[0][mt], 0, 0, 0);
                acc[1][mt] = __builtin_amdgcn_mfma_f32_16x16x32_bf16(a1, b, acc[1][mt], 0, 0, 0);
                acc[2][mt] = __builtin_amdgcn_mfma_f32_16x16x32_bf16(a2, b, acc[2][mt], 0, 0, 0);
                acc[3][mt] = __builtin_amdgcn_mfma_f32_16x16x32_bf16(a3, b, acc[3][mt], 0, 0, 0);
            }
        }
    }

    // epilogue: D reg r -> oc = ocw + nt*16 + q*4 + r, voxel col = l
    #pragma unroll
    for (int nt = 0; nt < 4; nt++) {
        const int ocb = ocw + nt * 16 + q * 4;
        const float4 bv = *(const float4*)(bias + ocb);
        #pragma unroll
        for (int mt = 0; mt < 4; mt++) {
            const int v = (z0 + mzw) * 2304 + (y0 + mt) * 48 + x0 + l;
            out[(size_t)(ocb + 0) * VOL + v] = acc[nt][mt][0] + bv.x;
            out[(size_t)(ocb + 1) * VOL + v] = acc[nt][mt][1] + bv.y;
            out[(size_t)(ocb + 2) * VOL + v] = acc[nt][mt][2] + bv.z;
            out[(size_t)(ocb + 3) * VOL + v] = acc[nt][mt][3] + bv.w;
        }
    }
}

// ---------------------------------------------------------------------------
// Per-channel mean / rstd (biased var).
__global__ __launch_bounds__(256) void chan_stats_kernel(
    const float* __restrict__ x, float* __restrict__ stats /* [128][2] */)
{
    const int c = blockIdx.x;
    const float* p = x + (size_t)c * VOL;
    float s = 0.f, s2 = 0.f;
    for (int i = threadIdx.x; i < VOL; i += 256) {
        const float v = p[i];
        s += v;
        s2 = fmaf(v, v, s2);
    }
    __shared__ float rs[256], rs2[256];
    rs[threadIdx.x] = s; rs2[threadIdx.x] = s2;
    __syncthreads();
    for (int off = 128; off > 0; off >>= 1) {
        if (threadIdx.x < off) {
            rs[threadIdx.x]  += rs[threadIdx.x + off];
            rs2[threadIdx.x] += rs2[threadIdx.x + off];
        }
        __syncthreads();
    }
    if (threadIdx.x == 0) {
        const float mean = rs[0] / (float)VOL;
        const float var  = rs2[0] / (float)VOL - mean * mean;
        stats[c * 2]     = mean;
        stats[c * 2 + 1] = rsqrtf(var + 1e-5f);
    }
}

__device__ __forceinline__ float gelu_exact(float h)
{
    return 0.5f * h * (1.f + erff(h * 0.70710678118654752f));
}

__global__ __launch_bounds__(256) void norm_gelu_kernel(
    const float* __restrict__ x, const float* __restrict__ stats,
    float* __restrict__ out)
{
    const size_t i = (size_t)blockIdx.x * 256 + threadIdx.x;  // float4 index
    const int c = (int)(i / (VOL / 4));
    const float mean = stats[c * 2], rstd = stats[c * 2 + 1];
    const float4 xv = ((const float4*)x)[i];
    float4 o;
    o.x = gelu_exact((xv.x - mean) * rstd);
    o.y = gelu_exact((xv.y - mean) * rstd);
    o.z = gelu_exact((xv.z - mean) * rstd);
    o.w = gelu_exact((xv.w - mean) * rstd);
    ((float4*)out)[i] = o;
}

// ---------------------------------------------------------------------------
// Transpose h [128][VOL] fp32 -> hT [VOL][128] bf16 (32x32 LDS tiles).
__global__ __launch_bounds__(256) void transpose128_bf16_kernel(
    const float* __restrict__ x, ushort* __restrict__ outT)
{
    __shared__ float tile[32][33];
    const int v0 = blockIdx.x * 32;
    const int c0 = blockIdx.y * 32;
    const int t = threadIdx.x;
    const int vl = t & 31, cl = t >> 5;
    #pragma unroll
    for (int i = 0; i < 4; i++)
        tile[cl + i * 8][vl] = x[(size_t)(c0 + cl + i * 8) * VOL + v0 + vl];
    __syncthreads();
    const int vw = t >> 3, cg = t & 7;
    ushort4 o;
    o.x = f2bf(tile[cg * 4 + 0][vw]);
    o.y = f2bf(tile[cg * 4 + 1][vw]);
    o.z = f2bf(tile[cg * 4 + 2][vw]);
    o.w = f2bf(tile[cg * 4 + 3][vw]);
    *(ushort4*)(outT + (size_t)(v0 + vw) * 128 + c0 + cg * 4) = o;
}

// ---------------------------------------------------------------------------
extern "C" void kernel_launch(void* const* d_in, const int* in_sizes, int n_in,
                              void* d_out, int out_size, void* d_ws, size_t ws_size,
                              hipStream_t stream)
{
    const float* src = (const float*)d_in[0];
    const float* tgt = (const float*)d_in[1];
    const float* psw = (const float*)d_in[2];
    const float* psb = (const float*)d_in[3];
    const float* ptw = (const float*)d_in[4];
    const float* ptb = (const float*)d_in[5];
    const float* e1w = (const float*)d_in[6];
    const float* e1b = (const float*)d_in[7];
    const float* e2w = (const float*)d_in[8];
    const float* e2b = (const float*)d_in[9];

    float* ws = (float*)d_ws;
    // Workspace (float-unit offsets; V = VOL). Lifetimes:
    //   sp [0,64V) + tp [64V,128V)      dead after corr -> h1 reuses [0,128V)
    //   featT bf16 [128V,304V)          dead after conv1 -> h2 reuses [128V,256V)
    //   h1T bf16 [304V,368V)
    //   w1T bf16 [368V,+608256 f), w2T bf16 (+221184 f), stats
    // Total ~167 MB.
    float*  sp    = ws;
    float*  tp    = ws + (size_t)64 * VOL;
    ushort* featT = (ushort*)(ws + (size_t)128 * VOL);
    float*  h1    = ws;
    float*  h2    = ws + (size_t)128 * VOL;
    ushort* h1T   = (ushort*)(ws + (size_t)304 * VOL);
    float*  w1Tf  = ws + (size_t)368 * VOL;
    ushort* w1T   = (ushort*)w1Tf;
    float*  w2Tf  = w1Tf + 608256;           // 27*128*352 ushorts = 608256 floats
    ushort* w2T   = (ushort*)w2Tf;
    float*  stats = w2Tf + 221184;           // 27*128*128 ushorts = 221184 floats

    wprep_kernel<346, 352><<<128, 256, 0, stream>>>(e1w, w1T);
    wprep_kernel<128, 128><<<128, 256, 0, stream>>>(e2w, w2T);

    proj_l2norm_kernel<<<432, 256, 0, stream>>>(src, psw, psb, sp);
    proj_l2norm_kernel<<<432, 256, 0, stream>>>(tgt, ptw, ptb, tp);
    corr_softmax_kernel<<<432, 256, 0, stream>>>(sp, tp, featT);

    conv3_mfma_kernel<352><<<864, 256, 0, stream>>>(featT, w1T, e1b, h1);
    chan_stats_kernel<<<128, 256, 0, stream>>>(h1, stats);
    norm_gelu_kernel<<<(128 * VOL) / 1024, 256, 0, stream>>>(h1, stats, h1);
    transpose128_bf16_kernel<<<dim3(3456, 4), 256, 0, stream>>>(h1, h1T);

    conv3_mfma_kernel<128><<<864, 256, 0, stream>>>(h1T, w2T, e2b, h2);
    chan_stats_kernel<<<128, 256, 0, stream>>>(h2, stats);
    norm_gelu_kernel<<<(128 * VOL) / 1024, 256, 0, stream>>>(h2, stats, (float*)d_out);
}

// Round 3
// 2772.588 us; speedup vs baseline: 5.8455x; 1.0037x over previous
//
#include <hip/hip_runtime.h>
#include <math.h>
#include <stdint.h>

#define VOL 110592   // 48*48*48
#define CINP 64      // input channels
#define PCH 64       // proj channels

typedef short short8 __attribute__((ext_vector_type(8)));
typedef float floatx4 __attribute__((ext_vector_type(4)));
typedef _Float16 h8 __attribute__((ext_vector_type(8)));
typedef _Float16 h2v __attribute__((ext_vector_type(2)));

__device__ __forceinline__ ushort f2bf(float f) {
    union { float f; uint32_t u; } v; v.f = f;
    uint32_t r = v.u + 0x7FFFu + ((v.u >> 16) & 1u);   // RNE
    return (ushort)(r >> 16);
}

__device__ __forceinline__ float hdot2(h2v a, h2v b, float c) {
#if __has_builtin(__builtin_amdgcn_fdot2)
    return __builtin_amdgcn_fdot2(a, b, c, false);
#else
    return fmaf((float)a[0], (float)b[0], fmaf((float)a[1], (float)b[1], c));
#endif
}

// ---------------------------------------------------------------------------
// 1x1x1 conv (64x64 matvec) + bias + channel L2-normalize. Voxel-major fp16
// output (post-norm values are in [-1,1] -> fp16-safe).
__global__ __launch_bounds__(256) void proj_l2norm_kernel(
    const float* __restrict__ x,   // [64][VOL]
    const float* __restrict__ w,   // [64][64]
    const float* __restrict__ b,   // [64]
    _Float16* __restrict__ out)    // [VOL][64]
{
    const int v = blockIdx.x * 256 + threadIdx.x;
    float xr[CINP];
    for (int ci = 0; ci < CINP; ci++)
        xr[ci] = x[(size_t)ci * VOL + v];

    float acc[PCH];
    for (int c = 0; c < PCH; c++) {
        float a = b[c];
        #pragma unroll
        for (int ci = 0; ci < CINP; ci++)
            a = fmaf(w[c * CINP + ci], xr[ci], a);
        acc[c] = a;
    }
    float s = 0.f;
    #pragma unroll
    for (int c = 0; c < PCH; c++) s += acc[c] * acc[c];
    const float inv = 1.0f / fmaxf(sqrtf(s), 1e-12f);
    #pragma unroll
    for (int c = 0; c < PCH; c++)
        out[(size_t)v * PCH + c] = (_Float16)(acc[c] * inv);
}

// ---------------------------------------------------------------------------
// Correlation, one dz-plane per blockIdx.y (49 offsets/thread). Edge-clamped.
// fp16 inputs, v_dot2_f32_f16 dots, fp32 accumulate. Writes corr channels
// [plane*49 .. +49) of featT[v][352] (bf16) and per-plane softmax partials:
//   partials[(plane*3+0)*VOL+v] = sum(e)      (note sum(e*dz) = dz*sum(e))
//   partials[(plane*3+1)*VOL+v] = sum(e*dy)
//   partials[(plane*3+2)*VOL+v] = sum(e*dx)
// |corr|<=1 (unit vectors) -> split softmax needs no max subtraction.
__global__ __launch_bounds__(256) void corr_plane_kernel(
    const _Float16* __restrict__ sp,   // [VOL][64]
    const _Float16* __restrict__ tp,   // [VOL][64]
    ushort* __restrict__ featT,        // [VOL][352] bf16
    float* __restrict__ partials)      // [7][3][VOL]
{
    const int v = blockIdx.x * 256 + threadIdx.x;
    const int plane = blockIdx.y;               // 0..6
    const int x = v % 48, y = (v / 48) % 48, z = v / 2304;
    const int zc = min(max(z + plane - 3, 0), 47);
    const int zbase = zc * 2304;

    h8 sr[8];
    const h8* sp8 = (const h8*)(sp + (size_t)v * PCH);
    #pragma unroll
    for (int i = 0; i < 8; i++) sr[i] = sp8[i];

    ushort* op = featT + (size_t)v * 352 + plane * 49;

    float ssum = 0.f, e1 = 0.f, e2 = 0.f;
    int k = 0;
    for (int dy = -3; dy <= 3; dy++) {
        const int yc = min(max(y + dy, 0), 47);
        const int rb = zbase + yc * 48;
        for (int dx = -3; dx <= 3; dx++) {
            const int xc = min(max(x + dx, 0), 47);
            const h8* tr = (const h8*)(tp + (size_t)(rb + xc) * PCH);
            float d0 = 0.f, d1 = 0.f, d2 = 0.f, d3 = 0.f;
            #pragma unroll
            for (int i = 0; i < 8; i++) {
                const h8 t = tr[i];
                const h8 s = sr[i];
                d0 = hdot2((h2v){s[0], s[1]}, (h2v){t[0], t[1]}, d0);
                d1 = hdot2((h2v){s[2], s[3]}, (h2v){t[2], t[3]}, d1);
                d2 = hdot2((h2v){s[4], s[5]}, (h2v){t[4], t[5]}, d2);
                d3 = hdot2((h2v){s[6], s[7]}, (h2v){t[6], t[7]}, d3);
            }
            const float dot = (d0 + d1) + (d2 + d3);
            op[k++] = f2bf(dot);
            const float e = __expf(dot);
            ssum += e;
            e1 += e * (float)dy;
            e2 += e * (float)dx;
        }
    }
    partials[((size_t)plane * 3 + 0) * VOL + v] = ssum;
    partials[((size_t)plane * 3 + 1) * VOL + v] = e1;
    partials[((size_t)plane * 3 + 2) * VOL + v] = e2;
}

// Combine per-plane partials -> expected-offset channels 343..345, zero pad.
__global__ __launch_bounds__(256) void eo_finalize_kernel(
    const float* __restrict__ partials, ushort* __restrict__ featT)
{
    const int v = blockIdx.x * 256 + threadIdx.x;
    float ssum = 0.f, e0 = 0.f, e1 = 0.f, e2 = 0.f;
    #pragma unroll
    for (int p = 0; p < 7; p++) {
        const float s = partials[((size_t)p * 3 + 0) * VOL + v];
        ssum += s;
        e0 += (float)(p - 3) * s;
        e1 += partials[((size_t)p * 3 + 1) * VOL + v];
        e2 += partials[((size_t)p * 3 + 2) * VOL + v];
    }
    const float inv = 1.f / ssum;
    ushort* op = featT + (size_t)v * 352;
    op[343] = f2bf(e0 * inv);
    op[344] = f2bf(e1 * inv);
    op[345] = f2bf(e2 * inv);
    #pragma unroll
    for (int j = 346; j < 352; j++) op[j] = 0;
}

// ---------------------------------------------------------------------------
// Weight pre-transpose: w[128][CIN][27] fp32 -> wT[27][128][CPAD] bf16 (pad 0).
template<int CIN, int CPAD>
__global__ __launch_bounds__(256) void wprep_kernel(
    const float* __restrict__ w, ushort* __restrict__ wTo)
{
    const int oc = blockIdx.x;
    for (int idx = threadIdx.x; idx < CPAD * 27; idx += 256) {
        const int icp = idx / 27, tap = idx - icp * 27;
        float val = 0.f;
        if (icp < CIN) val = w[((size_t)oc * CIN + icp) * 27 + tap];
        wTo[((size_t)tap * 128 + oc) * CPAD + icp] = f2bf(val);
    }
}

// ---------------------------------------------------------------------------
// Implicit-GEMM 3x3x3 conv via bf16 MFMA (zero padding).
// Block: 128 voxels (2z x 4y x 16x) x 128 oc. 4 waves: wave&1 -> oc half,
// wave>>1 -> voxel half. Wave computes 4 oc-subtiles x 4 voxel-subtiles.
template<int CPAD>
__global__ __launch_bounds__(256) void conv3_mfma_kernel(
    const ushort* __restrict__ xT,   // [VOL][CPAD] bf16
    const ushort* __restrict__ wT,   // [27][128][CPAD] bf16
    const float* __restrict__ bias,  // [128]
    float* __restrict__ out)         // [128][VOL] fp32
{
    const int blk = blockIdx.x;                 // 864 = 3(tx) * 12(ty) * 24(tz)
    const int tx = blk % 3, ty = (blk / 3) % 12, tz = blk / 36;
    const int x0 = tx * 16, y0 = ty * 4, z0 = tz * 2;
    const int t = threadIdx.x;
    const int wave = t >> 6;
    const int lane = t & 63;
    const int l = lane & 15;
    const int q = lane >> 4;
    const int ocw = (wave & 1) * 64;
    const int mzw = wave >> 1;

    __shared__ __align__(16) ushort win[432 * 40];

    floatx4 acc[4][4];
    #pragma unroll
    for (int i = 0; i < 4; i++)
        #pragma unroll
        for (int j = 0; j < 4; j++)
            acc[i][j] = (floatx4){0.f, 0.f, 0.f, 0.f};

    const int NCH = CPAD / 32;
    for (int ck = 0; ck < NCH; ck++) {
        __syncthreads();
        #pragma unroll
        for (int it = 0; it < 7; it++) {
            const int i = t + it * 256;
            if (i < 1728) {
                const int p = i >> 2, g = i & 3;
                const int wz = p / 108, pr = p - wz * 108;
                const int wy = pr / 18, wx = pr - wy * 18;
                const int gz = z0 + wz - 1, gy = y0 + wy - 1, gx = x0 + wx - 1;
                int4 val = {0, 0, 0, 0};
                if ((unsigned)gx < 48u && (unsigned)gy < 48u && (unsigned)gz < 48u) {
                    const size_t gv = (size_t)((gz * 2304) + gy * 48 + gx);
                    val = *(const int4*)(xT + gv * CPAD + ck * 32 + g * 8);
                }
                *(int4*)(&win[p * 40 + g * 8]) = val;
            }
        }
        __syncthreads();

        const ushort* wp0 = wT + (size_t)(ocw + l) * CPAD + ck * 32 + q * 8;
        for (int tap = 0; tap < 27; tap++) {
            const int dz = tap / 9, rr = tap - dz * 9;
            const int dy = rr / 3, dx = rr - dy * 3;
            const ushort* wp = wp0 + (size_t)tap * (128 * CPAD);
            const short8 a0 = *(const short8*)(wp);
            const short8 a1 = *(const short8*)(wp + 16 * CPAD);
            const short8 a2 = *(const short8*)(wp + 32 * CPAD);
            const short8 a3 = *(const short8*)(wp + 48 * CPAD);
            const int pb = ((mzw + dz) * 108 + dy * 18 + l + dx) * 40 + q * 8;
            #pragma unroll
            for (int mt = 0; mt < 4; mt++) {
                const short8 b = *(const short8*)(&win[pb + mt * 720]);
                acc[0][mt] = __builtin_amdgcn_mfma_f32_16x16x32_bf16(a0, b, acc[0][mt], 0, 0, 0);
                acc[1][mt] = __builtin_amdgcn_mfma_f32_16x16x32_bf16(a1, b, acc[1][mt], 0, 0, 0);
                acc[2][mt] = __builtin_amdgcn_mfma_f32_16x16x32_bf16(a2, b, acc[2][mt], 0, 0, 0);
                acc[3][mt] = __builtin_amdgcn_mfma_f32_16x16x32_bf16(a3, b, acc[3][mt], 0, 0, 0);
            }
        }
    }

    #pragma unroll
    for (int nt = 0; nt < 4; nt++) {
        const int ocb = ocw + nt * 16 + q * 4;
        const float4 bv = *(const float4*)(bias + ocb);
        #pragma unroll
        for (int mt = 0; mt < 4; mt++) {
            const int v = (z0 + mzw) * 2304 + (y0 + mt) * 48 + x0 + l;
            out[(size_t)(ocb + 0) * VOL + v] = acc[nt][mt][0] + bv.x;
            out[(size_t)(ocb + 1) * VOL + v] = acc[nt][mt][1] + bv.y;
            out[(size_t)(ocb + 2) * VOL + v] = acc[nt][mt][2] + bv.z;
            out[(size_t)(ocb + 3) * VOL + v] = acc[nt][mt][3] + bv.w;
        }
    }
}

// ---------------------------------------------------------------------------
// Per-channel mean / rstd (biased var).
__global__ __launch_bounds__(256) void chan_stats_kernel(
    const float* __restrict__ x, float* __restrict__ stats /* [128][2] */)
{
    const int c = blockIdx.x;
    const float* p = x + (size_t)c * VOL;
    float s = 0.f, s2 = 0.f;
    for (int i = threadIdx.x; i < VOL; i += 256) {
        const float v = p[i];
        s += v;
        s2 = fmaf(v, v, s2);
    }
    __shared__ float rs[256], rs2[256];
    rs[threadIdx.x] = s; rs2[threadIdx.x] = s2;
    __syncthreads();
    for (int off = 128; off > 0; off >>= 1) {
        if (threadIdx.x < off) {
            rs[threadIdx.x]  += rs[threadIdx.x + off];
            rs2[threadIdx.x] += rs2[threadIdx.x + off];
        }
        __syncthreads();
    }
    if (threadIdx.x == 0) {
        const float mean = rs[0] / (float)VOL;
        const float var  = rs2[0] / (float)VOL - mean * mean;
        stats[c * 2]     = mean;
        stats[c * 2 + 1] = rsqrtf(var + 1e-5f);
    }
}

__device__ __forceinline__ float gelu_exact(float h)
{
    return 0.5f * h * (1.f + erff(h * 0.70710678118654752f));
}

__global__ __launch_bounds__(256) void norm_gelu_kernel(
    const float* __restrict__ x, const float* __restrict__ stats,
    float* __restrict__ out)
{
    const size_t i = (size_t)blockIdx.x * 256 + threadIdx.x;  // float4 index
    const int c = (int)(i / (VOL / 4));
    const float mean = stats[c * 2], rstd = stats[c * 2 + 1];
    const float4 xv = ((const float4*)x)[i];
    float4 o;
    o.x = gelu_exact((xv.x - mean) * rstd);
    o.y = gelu_exact((xv.y - mean) * rstd);
    o.z = gelu_exact((xv.z - mean) * rstd);
    o.w = gelu_exact((xv.w - mean) * rstd);
    ((float4*)out)[i] = o;
}

// ---------------------------------------------------------------------------
// Transpose h [128][VOL] fp32 -> hT [VOL][128] bf16 (32x32 LDS tiles).
__global__ __launch_bounds__(256) void transpose128_bf16_kernel(
    const float* __restrict__ x, ushort* __restrict__ outT)
{
    __shared__ float tile[32][33];
    const int v0 = blockIdx.x * 32;
    const int c0 = blockIdx.y * 32;
    const int t = threadIdx.x;
    const int vl = t & 31, cl = t >> 5;
    #pragma unroll
    for (int i = 0; i < 4; i++)
        tile[cl + i * 8][vl] = x[(size_t)(c0 + cl + i * 8) * VOL + v0 + vl];
    __syncthreads();
    const int vw = t >> 3, cg = t & 7;
    ushort4 o;
    o.x = f2bf(tile[cg * 4 + 0][vw]);
    o.y = f2bf(tile[cg * 4 + 1][vw]);
    o.z = f2bf(tile[cg * 4 + 2][vw]);
    o.w = f2bf(tile[cg * 4 + 3][vw]);
    *(ushort4*)(outT + (size_t)(v0 + vw) * 128 + c0 + cg * 4) = o;
}

// ---------------------------------------------------------------------------
extern "C" void kernel_launch(void* const* d_in, const int* in_sizes, int n_in,
                              void* d_out, int out_size, void* d_ws, size_t ws_size,
                              hipStream_t stream)
{
    const float* src = (const float*)d_in[0];
    const float* tgt = (const float*)d_in[1];
    const float* psw = (const float*)d_in[2];
    const float* psb = (const float*)d_in[3];
    const float* ptw = (const float*)d_in[4];
    const float* ptb = (const float*)d_in[5];
    const float* e1w = (const float*)d_in[6];
    const float* e1b = (const float*)d_in[7];
    const float* e2w = (const float*)d_in[8];
    const float* e2b = (const float*)d_in[9];

    float* ws = (float*)d_ws;
    // Workspace (float-unit offsets; V = VOL). Lifetimes:
    //   sp/tp fp16 [0,64V)          dead after corr -> h1 (fp32) reuses [0,128V)
    //   featT bf16 [128V,304V)      dead after conv1 -> h2 reuses [128V,256V)
    //   h1T bf16 [304V,368V)
    //   w1T bf16 [368V..), w2T, stats, partials (7x3xV)
    _Float16* sp  = (_Float16*)ws;                         // [VOL][64] = 32V floats
    _Float16* tp  = (_Float16*)(ws + (size_t)32 * VOL);
    ushort* featT = (ushort*)(ws + (size_t)128 * VOL);
    float*  h1    = ws;
    float*  h2    = ws + (size_t)128 * VOL;
    ushort* h1T   = (ushort*)(ws + (size_t)304 * VOL);
    float*  w1Tf  = ws + (size_t)368 * VOL;
    ushort* w1T   = (ushort*)w1Tf;
    float*  w2Tf  = w1Tf + 608256;           // 27*128*352 ushorts
    ushort* w2T   = (ushort*)w2Tf;
    float*  stats = w2Tf + 221184;           // 27*128*128 ushorts
    float*  partials = stats + 256;          // 7*3*VOL floats

    wprep_kernel<346, 352><<<128, 256, 0, stream>>>(e1w, w1T);
    wprep_kernel<128, 128><<<128, 256, 0, stream>>>(e2w, w2T);

    proj_l2norm_kernel<<<432, 256, 0, stream>>>(src, psw, psb, sp);
    proj_l2norm_kernel<<<432, 256, 0, stream>>>(tgt, ptw, ptb, tp);
    corr_plane_kernel<<<dim3(432, 7), 256, 0, stream>>>(sp, tp, featT, partials);
    eo_finalize_kernel<<<432, 256, 0, stream>>>(partials, featT);

    conv3_mfma_kernel<352><<<864, 256, 0, stream>>>(featT, w1T, e1b, h1);
    chan_stats_kernel<<<128, 256, 0, stream>>>(h1, stats);
    norm_gelu_kernel<<<(128 * VOL) / 1024, 256, 0, stream>>>(h1, stats, h1);
    transpose128_bf16_kernel<<<dim3(3456, 4), 256, 0, stream>>>(h1, h1T);

    conv3_mfma_kernel<128><<<864, 256, 0, stream>>>(h1T, w2T, e2b, h2);
    chan_stats_kernel<<<128, 256, 0, stream>>>(h2, stats);
    norm_gelu_kernel<<<(128 * VOL) / 1024, 256, 0, stream>>>(h2, stats, (float*)d_out);
}

// Round 4
// 1664.873 us; speedup vs baseline: 9.7347x; 1.6653x over previous
//
#include <hip/hip_runtime.h>
#include <math.h>
#include <stdint.h>

#define VOL 110592   // 48*48*48
#define CINP 64      // input channels
#define PCH 64       // proj channels

typedef short short8 __attribute__((ext_vector_type(8)));
typedef float floatx4 __attribute__((ext_vector_type(4)));
typedef _Float16 h8 __attribute__((ext_vector_type(8)));
typedef _Float16 h2v __attribute__((ext_vector_type(2)));

__device__ __forceinline__ ushort f2bf(float f) {
    union { float f; uint32_t u; } v; v.f = f;
    uint32_t r = v.u + 0x7FFFu + ((v.u >> 16) & 1u);   // RNE
    return (ushort)(r >> 16);
}

__device__ __forceinline__ float hdot2(h2v a, h2v b, float c) {
#if __has_builtin(__builtin_amdgcn_fdot2)
    return __builtin_amdgcn_fdot2(a, b, c, false);
#else
    return fmaf((float)a[0], (float)b[0], fmaf((float)a[1], (float)b[1], c));
#endif
}

// ---------------------------------------------------------------------------
// 1x1x1 conv (64x64 matvec) + bias + channel L2-normalize. Voxel-major fp16
// output (post-norm values are in [-1,1] -> fp16-safe).
__global__ __launch_bounds__(256) void proj_l2norm_kernel(
    const float* __restrict__ x,   // [64][VOL]
    const float* __restrict__ w,   // [64][64]
    const float* __restrict__ b,   // [64]
    _Float16* __restrict__ out)    // [VOL][64]
{
    const int v = blockIdx.x * 256 + threadIdx.x;
    float xr[CINP];
    for (int ci = 0; ci < CINP; ci++)
        xr[ci] = x[(size_t)ci * VOL + v];

    float acc[PCH];
    for (int c = 0; c < PCH; c++) {
        float a = b[c];
        #pragma unroll
        for (int ci = 0; ci < CINP; ci++)
            a = fmaf(w[c * CINP + ci], xr[ci], a);
        acc[c] = a;
    }
    float s = 0.f;
    #pragma unroll
    for (int c = 0; c < PCH; c++) s += acc[c] * acc[c];
    const float inv = 1.0f / fmaxf(sqrtf(s), 1e-12f);
    #pragma unroll
    for (int c = 0; c < PCH; c++)
        out[(size_t)v * PCH + c] = (_Float16)(acc[c] * inv);
}

// ---------------------------------------------------------------------------
// Fused correlation (343 offsets, edge-clamped) + softmax expected-offset.
// Lane layout: lane = (vg, c8): 8 voxels x 8 channel-chunks per wave.
// Per offset: 16B/lane coalesced load (1 KB/wave), 4x v_dot2_f32_f16,
// 3-step shfl_xor butterfly -> full 64-ch dot replicated in group lanes.
// Corr values buffered in LDS (row stride 360 = conflict-free for the 8-lane
// predicated ds_write_b16), then block writes 32 complete 704-B featT rows
// with coalesced 16-B stores (no cross-block false sharing).
__global__ __launch_bounds__(256) void corr_fused_kernel(
    const _Float16* __restrict__ sp,   // [VOL][64]
    const _Float16* __restrict__ tp,   // [VOL][64]
    ushort* __restrict__ featT)        // [VOL][352] bf16
{
    const int t  = threadIdx.x;
    const int c8 = t & 7;              // channel chunk (8 fp16 = 16 B)
    const int vg = t >> 3;             // voxel within block (0..31)
    const int v  = blockIdx.x * 32 + vg;
    const int x = v % 48, y = (v / 48) % 48, z = v / 2304;

    __shared__ __align__(16) ushort lds[32 * 360];   // 23 KB

    const h8 s = *(const h8*)(sp + (size_t)v * PCH + c8 * 8);

    float ssum = 0.f, e0 = 0.f, e1 = 0.f, e2 = 0.f;
    int k = 0;
    for (int dz = -3; dz <= 3; dz++) {
        const int zb = min(max(z + dz, 0), 47) * 2304;
        const float fdz = (float)dz;
        for (int dy = -3; dy <= 3; dy++) {
            const int rb = zb + min(max(y + dy, 0), 47) * 48;
            const float fdy = (float)dy;
            #pragma unroll
            for (int dx = -3; dx <= 3; dx++) {
                const int xc = min(max(x + dx, 0), 47);
                const h8 tv = *(const h8*)(tp + (size_t)(rb + xc) * PCH + c8 * 8);
                float d0 = hdot2((h2v){s[0], s[1]}, (h2v){tv[0], tv[1]}, 0.f);
                d0 = hdot2((h2v){s[2], s[3]}, (h2v){tv[2], tv[3]}, d0);
                float d1 = hdot2((h2v){s[4], s[5]}, (h2v){tv[4], tv[5]}, 0.f);
                d1 = hdot2((h2v){s[6], s[7]}, (h2v){tv[6], tv[7]}, d1);
                float dot = d0 + d1;
                dot += __shfl_xor(dot, 1);
                dot += __shfl_xor(dot, 2);
                dot += __shfl_xor(dot, 4);     // replicated across 8 group lanes
                if (c8 == 0) lds[vg * 360 + k] = f2bf(dot);
                const float e = __expf(dot);   // |dot|<=1: no max-subtraction
                ssum += e;
                e0 += e * fdz;
                e1 += e * fdy;
                e2 += e * (float)dx;
                k++;
            }
        }
    }

    if (c8 == 0) {
        const float inv = 1.f / ssum;
        lds[vg * 360 + 343] = f2bf(e0 * inv);
        lds[vg * 360 + 344] = f2bf(e1 * inv);
        lds[vg * 360 + 345] = f2bf(e2 * inv);
        #pragma unroll
        for (int j = 346; j < 352; j++) lds[vg * 360 + j] = 0;
    }
    __syncthreads();

    // coalesced copy-out: 32 rows x 352 ushorts = 1408 x 16B chunks
    ushort* ob = featT + (size_t)blockIdx.x * 32 * 352;
    #pragma unroll
    for (int j = 0; j < 6; j++) {
        const int idx = t + j * 256;
        if (idx < 1408) {
            const int row = idx / 44, col = (idx % 44) * 8;  // 44 chunks/row
            *(int4*)(ob + (size_t)row * 352 + col) = *(const int4*)(&lds[row * 360 + col]);
        }
    }
}

// ---------------------------------------------------------------------------
// Weight pre-transpose: w[128][CIN][27] fp32 -> wT[27][128][CPAD] bf16 (pad 0).
template<int CIN, int CPAD>
__global__ __launch_bounds__(256) void wprep_kernel(
    const float* __restrict__ w, ushort* __restrict__ wTo)
{
    const int oc = blockIdx.x;
    for (int idx = threadIdx.x; idx < CPAD * 27; idx += 256) {
        const int icp = idx / 27, tap = idx - icp * 27;
        float val = 0.f;
        if (icp < CIN) val = w[((size_t)oc * CIN + icp) * 27 + tap];
        wTo[((size_t)tap * 128 + oc) * CPAD + icp] = f2bf(val);
    }
}

// ---------------------------------------------------------------------------
// Implicit-GEMM 3x3x3 conv via bf16 MFMA (zero padding).
// Block: 128 voxels (2z x 4y x 16x) x 128 oc. 4 waves: wave&1 -> oc half,
// wave>>1 -> voxel half. Wave computes 4 oc-subtiles x 4 voxel-subtiles.
template<int CPAD>
__global__ __launch_bounds__(256) void conv3_mfma_kernel(
    const ushort* __restrict__ xT,   // [VOL][CPAD] bf16
    const ushort* __restrict__ wT,   // [27][128][CPAD] bf16
    const float* __restrict__ bias,  // [128]
    float* __restrict__ out)         // [128][VOL] fp32
{
    const int blk = blockIdx.x;                 // 864 = 3(tx) * 12(ty) * 24(tz)
    const int tx = blk % 3, ty = (blk / 3) % 12, tz = blk / 36;
    const int x0 = tx * 16, y0 = ty * 4, z0 = tz * 2;
    const int t = threadIdx.x;
    const int wave = t >> 6;
    const int lane = t & 63;
    const int l = lane & 15;
    const int q = lane >> 4;
    const int ocw = (wave & 1) * 64;
    const int mzw = wave >> 1;

    __shared__ __align__(16) ushort win[432 * 40];

    floatx4 acc[4][4];
    #pragma unroll
    for (int i = 0; i < 4; i++)
        #pragma unroll
        for (int j = 0; j < 4; j++)
            acc[i][j] = (floatx4){0.f, 0.f, 0.f, 0.f};

    const int NCH = CPAD / 32;
    for (int ck = 0; ck < NCH; ck++) {
        __syncthreads();
        #pragma unroll
        for (int it = 0; it < 7; it++) {
            const int i = t + it * 256;
            if (i < 1728) {
                const int p = i >> 2, g = i & 3;
                const int wz = p / 108, pr = p - wz * 108;
                const int wy = pr / 18, wx = pr - wy * 18;
                const int gz = z0 + wz - 1, gy = y0 + wy - 1, gx = x0 + wx - 1;
                int4 val = {0, 0, 0, 0};
                if ((unsigned)gx < 48u && (unsigned)gy < 48u && (unsigned)gz < 48u) {
                    const size_t gv = (size_t)((gz * 2304) + gy * 48 + gx);
                    val = *(const int4*)(xT + gv * CPAD + ck * 32 + g * 8);
                }
                *(int4*)(&win[p * 40 + g * 8]) = val;
            }
        }
        __syncthreads();

        const ushort* wp0 = wT + (size_t)(ocw + l) * CPAD + ck * 32 + q * 8;
        for (int tap = 0; tap < 27; tap++) {
            const int dz = tap / 9, rr = tap - dz * 9;
            const int dy = rr / 3, dx = rr - dy * 3;
            const ushort* wp = wp0 + (size_t)tap * (128 * CPAD);
            const short8 a0 = *(const short8*)(wp);
            const short8 a1 = *(const short8*)(wp + 16 * CPAD);
            const short8 a2 = *(const short8*)(wp + 32 * CPAD);
            const short8 a3 = *(const short8*)(wp + 48 * CPAD);
            const int pb = ((mzw + dz) * 108 + dy * 18 + l + dx) * 40 + q * 8;
            #pragma unroll
            for (int mt = 0; mt < 4; mt++) {
                const short8 b = *(const short8*)(&win[pb + mt * 720]);
                acc[0][mt] = __builtin_amdgcn_mfma_f32_16x16x32_bf16(a0, b, acc[0][mt], 0, 0, 0);
                acc[1][mt] = __builtin_amdgcn_mfma_f32_16x16x32_bf16(a1, b, acc[1][mt], 0, 0, 0);
                acc[2][mt] = __builtin_amdgcn_mfma_f32_16x16x32_bf16(a2, b, acc[2][mt], 0, 0, 0);
                acc[3][mt] = __builtin_amdgcn_mfma_f32_16x16x32_bf16(a3, b, acc[3][mt], 0, 0, 0);
            }
        }
    }

    #pragma unroll
    for (int nt = 0; nt < 4; nt++) {
        const int ocb = ocw + nt * 16 + q * 4;
        const float4 bv = *(const float4*)(bias + ocb);
        #pragma unroll
        for (int mt = 0; mt < 4; mt++) {
            const int v = (z0 + mzw) * 2304 + (y0 + mt) * 48 + x0 + l;
            out[(size_t)(ocb + 0) * VOL + v] = acc[nt][mt][0] + bv.x;
            out[(size_t)(ocb + 1) * VOL + v] = acc[nt][mt][1] + bv.y;
            out[(size_t)(ocb + 2) * VOL + v] = acc[nt][mt][2] + bv.z;
            out[(size_t)(ocb + 3) * VOL + v] = acc[nt][mt][3] + bv.w;
        }
    }
}

// ---------------------------------------------------------------------------
// Per-channel mean / rstd (biased var).
__global__ __launch_bounds__(256) void chan_stats_kernel(
    const float* __restrict__ x, float* __restrict__ stats /* [128][2] */)
{
    const int c = blockIdx.x;
    const float* p = x + (size_t)c * VOL;
    float s = 0.f, s2 = 0.f;
    for (int i = threadIdx.x; i < VOL; i += 256) {
        const float v = p[i];
        s += v;
        s2 = fmaf(v, v, s2);
    }
    __shared__ float rs[256], rs2[256];
    rs[threadIdx.x] = s; rs2[threadIdx.x] = s2;
    __syncthreads();
    for (int off = 128; off > 0; off >>= 1) {
        if (threadIdx.x < off) {
            rs[threadIdx.x]  += rs[threadIdx.x + off];
            rs2[threadIdx.x] += rs2[threadIdx.x + off];
        }
        __syncthreads();
    }
    if (threadIdx.x == 0) {
        const float mean = rs[0] / (float)VOL;
        const float var  = rs2[0] / (float)VOL - mean * mean;
        stats[c * 2]     = mean;
        stats[c * 2 + 1] = rsqrtf(var + 1e-5f);
    }
}

__device__ __forceinline__ float gelu_exact(float h)
{
    return 0.5f * h * (1.f + erff(h * 0.70710678118654752f));
}

__global__ __launch_bounds__(256) void norm_gelu_kernel(
    const float* __restrict__ x, const float* __restrict__ stats,
    float* __restrict__ out)
{
    const size_t i = (size_t)blockIdx.x * 256 + threadIdx.x;  // float4 index
    const int c = (int)(i / (VOL / 4));
    const float mean = stats[c * 2], rstd = stats[c * 2 + 1];
    const float4 xv = ((const float4*)x)[i];
    float4 o;
    o.x = gelu_exact((xv.x - mean) * rstd);
    o.y = gelu_exact((xv.y - mean) * rstd);
    o.z = gelu_exact((xv.z - mean) * rstd);
    o.w = gelu_exact((xv.w - mean) * rstd);
    ((float4*)out)[i] = o;
}

// ---------------------------------------------------------------------------
// Transpose h [128][VOL] fp32 -> hT [VOL][128] bf16 (32x32 LDS tiles).
__global__ __launch_bounds__(256) void transpose128_bf16_kernel(
    const float* __restrict__ x, ushort* __restrict__ outT)
{
    __shared__ float tile[32][33];
    const int v0 = blockIdx.x * 32;
    const int c0 = blockIdx.y * 32;
    const int t = threadIdx.x;
    const int vl = t & 31, cl = t >> 5;
    #pragma unroll
    for (int i = 0; i < 4; i++)
        tile[cl + i * 8][vl] = x[(size_t)(c0 + cl + i * 8) * VOL + v0 + vl];
    __syncthreads();
    const int vw = t >> 3, cg = t & 7;
    ushort4 o;
    o.x = f2bf(tile[cg * 4 + 0][vw]);
    o.y = f2bf(tile[cg * 4 + 1][vw]);
    o.z = f2bf(tile[cg * 4 + 2][vw]);
    o.w = f2bf(tile[cg * 4 + 3][vw]);
    *(ushort4*)(outT + (size_t)(v0 + vw) * 128 + c0 + cg * 4) = o;
}

// ---------------------------------------------------------------------------
extern "C" void kernel_launch(void* const* d_in, const int* in_sizes, int n_in,
                              void* d_out, int out_size, void* d_ws, size_t ws_size,
                              hipStream_t stream)
{
    const float* src = (const float*)d_in[0];
    const float* tgt = (const float*)d_in[1];
    const float* psw = (const float*)d_in[2];
    const float* psb = (const float*)d_in[3];
    const float* ptw = (const float*)d_in[4];
    const float* ptb = (const float*)d_in[5];
    const float* e1w = (const float*)d_in[6];
    const float* e1b = (const float*)d_in[7];
    const float* e2w = (const float*)d_in[8];
    const float* e2b = (const float*)d_in[9];

    float* ws = (float*)d_ws;
    // Workspace (float-unit offsets; V = VOL). Lifetimes:
    //   sp/tp fp16 [0,64V)          dead after corr -> h1 (fp32) reuses [0,128V)
    //   featT bf16 [128V,304V)      dead after conv1 -> h2 reuses [128V,256V)
    //   h1T bf16 [304V,368V)
    //   w1T bf16 [368V..), w2T, stats
    _Float16* sp  = (_Float16*)ws;                         // [VOL][64] = 32V floats
    _Float16* tp  = (_Float16*)(ws + (size_t)32 * VOL);
    ushort* featT = (ushort*)(ws + (size_t)128 * VOL);
    float*  h1    = ws;
    float*  h2    = ws + (size_t)128 * VOL;
    ushort* h1T   = (ushort*)(ws + (size_t)304 * VOL);
    float*  w1Tf  = ws + (size_t)368 * VOL;
    ushort* w1T   = (ushort*)w1Tf;
    float*  w2Tf  = w1Tf + 608256;           // 27*128*352 ushorts
    ushort* w2T   = (ushort*)w2Tf;
    float*  stats = w2Tf + 221184;           // 27*128*128 ushorts

    wprep_kernel<346, 352><<<128, 256, 0, stream>>>(e1w, w1T);
    wprep_kernel<128, 128><<<128, 256, 0, stream>>>(e2w, w2T);

    proj_l2norm_kernel<<<432, 256, 0, stream>>>(src, psw, psb, sp);
    proj_l2norm_kernel<<<432, 256, 0, stream>>>(tgt, ptw, ptb, tp);
    corr_fused_kernel<<<3456, 256, 0, stream>>>(sp, tp, featT);

    conv3_mfma_kernel<352><<<864, 256, 0, stream>>>(featT, w1T, e1b, h1);
    chan_stats_kernel<<<128, 256, 0, stream>>>(h1, stats);
    norm_gelu_kernel<<<(128 * VOL) / 1024, 256, 0, stream>>>(h1, stats, h1);
    transpose128_bf16_kernel<<<dim3(3456, 4), 256, 0, stream>>>(h1, h1T);

    conv3_mfma_kernel<128><<<864, 256, 0, stream>>>(h1T, w2T, e2b, h2);
    chan_stats_kernel<<<128, 256, 0, stream>>>(h2, stats);
    norm_gelu_kernel<<<(128 * VOL) / 1024, 256, 0, stream>>>(h2, stats, (float*)d_out);
}

// Round 5
// 1528.741 us; speedup vs baseline: 10.6016x; 1.0890x over previous
//
#include <hip/hip_runtime.h>
#include <math.h>
#include <stdint.h>

#define VOL 110592   // 48*48*48
#define CINP 64      // input channels
#define PCH 64       // proj channels

typedef short short8 __attribute__((ext_vector_type(8)));
typedef float floatx4 __attribute__((ext_vector_type(4)));
typedef _Float16 h8 __attribute__((ext_vector_type(8)));
typedef _Float16 h2v __attribute__((ext_vector_type(2)));

__device__ __forceinline__ ushort f2bf(float f) {
    union { float f; uint32_t u; } v; v.f = f;
    uint32_t r = v.u + 0x7FFFu + ((v.u >> 16) & 1u);   // RNE
    return (ushort)(r >> 16);
}

__device__ __forceinline__ float hdot2(h2v a, h2v b, float c) {
#if __has_builtin(__builtin_amdgcn_fdot2)
    return __builtin_amdgcn_fdot2(a, b, c, false);
#else
    return fmaf((float)a[0], (float)b[0], fmaf((float)a[1], (float)b[1], c));
#endif
}

// ---------------------------------------------------------------------------
// 1x1x1 conv (64x64 matvec) + bias + channel L2-normalize. fp16 voxel-major
// output (post-norm values in [-1,1] -> fp16-safe).
__global__ __launch_bounds__(256) void proj_l2norm_kernel(
    const float* __restrict__ x,   // [64][VOL]
    const float* __restrict__ w,   // [64][64]
    const float* __restrict__ b,   // [64]
    _Float16* __restrict__ out)    // [VOL][64]
{
    const int v = blockIdx.x * 256 + threadIdx.x;
    float xr[CINP];
    for (int ci = 0; ci < CINP; ci++)
        xr[ci] = x[(size_t)ci * VOL + v];

    float acc[PCH];
    for (int c = 0; c < PCH; c++) {
        float a = b[c];
        #pragma unroll
        for (int ci = 0; ci < CINP; ci++)
            a = fmaf(w[c * CINP + ci], xr[ci], a);
        acc[c] = a;
    }
    float s = 0.f;
    #pragma unroll
    for (int c = 0; c < PCH; c++) s += acc[c] * acc[c];
    const float inv = 1.0f / fmaxf(sqrtf(s), 1e-12f);
    #pragma unroll
    for (int c = 0; c < PCH; c++)
        out[(size_t)v * PCH + c] = (_Float16)(acc[c] * inv);
}

// ---------------------------------------------------------------------------
// Fused correlation (343 offsets, edge-clamped) + softmax expected-offset.
// Lane = (vg, c8): 8 voxels x 8 channel-chunks per wave; 16B/lane coalesced
// loads, v_dot2_f32_f16, 3-step shfl_xor butterfly. Corr rows buffered in LDS
// then written out with coalesced 16-B stores.
__global__ __launch_bounds__(256) void corr_fused_kernel(
    const _Float16* __restrict__ sp,   // [VOL][64]
    const _Float16* __restrict__ tp,   // [VOL][64]
    ushort* __restrict__ featT)        // [VOL][352] bf16
{
    const int t  = threadIdx.x;
    const int c8 = t & 7;
    const int vg = t >> 3;
    const int v  = blockIdx.x * 32 + vg;
    const int x = v % 48, y = (v / 48) % 48, z = v / 2304;

    __shared__ __align__(16) ushort lds[32 * 360];   // 23 KB

    const h8 s = *(const h8*)(sp + (size_t)v * PCH + c8 * 8);

    float ssum = 0.f, e0 = 0.f, e1 = 0.f, e2 = 0.f;
    int k = 0;
    for (int dz = -3; dz <= 3; dz++) {
        const int zb = min(max(z + dz, 0), 47) * 2304;
        const float fdz = (float)dz;
        for (int dy = -3; dy <= 3; dy++) {
            const int rb = zb + min(max(y + dy, 0), 47) * 48;
            const float fdy = (float)dy;
            #pragma unroll
            for (int dx = -3; dx <= 3; dx++) {
                const int xc = min(max(x + dx, 0), 47);
                const h8 tv = *(const h8*)(tp + (size_t)(rb + xc) * PCH + c8 * 8);
                float d0 = hdot2((h2v){s[0], s[1]}, (h2v){tv[0], tv[1]}, 0.f);
                d0 = hdot2((h2v){s[2], s[3]}, (h2v){tv[2], tv[3]}, d0);
                float d1 = hdot2((h2v){s[4], s[5]}, (h2v){tv[4], tv[5]}, 0.f);
                d1 = hdot2((h2v){s[6], s[7]}, (h2v){tv[6], tv[7]}, d1);
                float dot = d0 + d1;
                dot += __shfl_xor(dot, 1);
                dot += __shfl_xor(dot, 2);
                dot += __shfl_xor(dot, 4);
                if (c8 == 0) lds[vg * 360 + k] = f2bf(dot);
                const float e = __expf(dot);   // |dot|<=1: no max-subtraction
                ssum += e;
                e0 += e * fdz;
                e1 += e * fdy;
                e2 += e * (float)dx;
                k++;
            }
        }
    }

    if (c8 == 0) {
        const float inv = 1.f / ssum;
        lds[vg * 360 + 343] = f2bf(e0 * inv);
        lds[vg * 360 + 344] = f2bf(e1 * inv);
        lds[vg * 360 + 345] = f2bf(e2 * inv);
        #pragma unroll
        for (int j = 346; j < 352; j++) lds[vg * 360 + j] = 0;
    }
    __syncthreads();

    ushort* ob = featT + (size_t)blockIdx.x * 32 * 352;
    #pragma unroll
    for (int j = 0; j < 6; j++) {
        const int idx = t + j * 256;
        if (idx < 1408) {
            const int row = idx / 44, col = (idx % 44) * 8;
            *(int4*)(ob + (size_t)row * 352 + col) = *(const int4*)(&lds[row * 360 + col]);
        }
    }
}

// ---------------------------------------------------------------------------
// Weight pre-transpose: w[128][CIN][27] fp32 -> wT[27][128][CPAD] bf16 (pad 0).
template<int CIN, int CPAD>
__global__ __launch_bounds__(256) void wprep_kernel(
    const float* __restrict__ w, ushort* __restrict__ wTo)
{
    const int oc = blockIdx.x;
    for (int idx = threadIdx.x; idx < CPAD * 27; idx += 256) {
        const int icp = idx / 27, tap = idx - icp * 27;
        float val = 0.f;
        if (icp < CIN) val = w[((size_t)oc * CIN + icp) * 27 + tap];
        wTo[((size_t)tap * 128 + oc) * CPAD + icp] = f2bf(val);
    }
}

// ---------------------------------------------------------------------------
// Implicit-GEMM 3x3x3 conv via bf16 MFMA (zero padding), pipelined:
//  - staging register-prefetch: chunk ck+1's global loads are issued right
//    after chunk ck's LDS writes and stay in flight through ck's compute
//  - weight loads batched per (dz,dy) group (12 x 16B), hidden behind the
//    previous group's 48 MFMAs
// Block: 128 voxels (2z x 4y x 16x) x 128 oc, 4 waves.
template<int CPAD>
__global__ __launch_bounds__(256) void conv3_mfma_kernel(
    const ushort* __restrict__ xT,   // [VOL][CPAD] bf16
    const ushort* __restrict__ wT,   // [27][128][CPAD] bf16
    const float* __restrict__ bias,  // [128]
    float* __restrict__ out)         // [128][VOL] fp32
{
    const int blk = blockIdx.x;                 // 864 = 3(tx) * 12(ty) * 24(tz)
    const int tx = blk % 3, ty = (blk / 3) % 12, tz = blk / 36;
    const int x0 = tx * 16, y0 = ty * 4, z0 = tz * 2;
    const int t = threadIdx.x;
    const int wave = t >> 6;
    const int lane = t & 63;
    const int l = lane & 15;
    const int q = lane >> 4;
    const int ocw = (wave & 1) * 64;
    const int mzw = wave >> 1;

    __shared__ __align__(16) ushort win[432 * 40];

    // per-lane staging addresses (7 slots of: 1728 = 432 pos x 4 granules)
    const ushort* sa[7];
    int lp[7], lg[7];
    #pragma unroll
    for (int it = 0; it < 7; it++) {
        const int i = t + it * 256;
        sa[it] = nullptr;
        lp[it] = 0; lg[it] = 0;
        if (i < 1728) {
            const int p = i >> 2, g = i & 3;
            lp[it] = p; lg[it] = g;
            const int wz = p / 108, pr = p - wz * 108;
            const int wy = pr / 18, wx = pr - wy * 18;
            const int gz = z0 + wz - 1, gy = y0 + wy - 1, gx = x0 + wx - 1;
            if ((unsigned)gx < 48u && (unsigned)gy < 48u && (unsigned)gz < 48u)
                sa[it] = xT + (size_t)(gz * 2304 + gy * 48 + gx) * CPAD + g * 8;
        }
    }

    const int4 zero4 = {0, 0, 0, 0};
    int4 pre[7];
    #pragma unroll
    for (int it = 0; it < 7; it++)
        pre[it] = sa[it] ? *(const int4*)(sa[it]) : zero4;

    floatx4 acc[4][4];
    #pragma unroll
    for (int i = 0; i < 4; i++)
        #pragma unroll
        for (int j = 0; j < 4; j++)
            acc[i][j] = (floatx4){0.f, 0.f, 0.f, 0.f};

    const int NCH = CPAD / 32;
    #pragma unroll 1
    for (int ck = 0; ck < NCH; ck++) {
        __syncthreads();
        #pragma unroll
        for (int it = 0; it < 7; it++) {
            if (t + it * 256 < 1728)
                *(int4*)(&win[lp[it] * 40 + lg[it] * 8]) = pre[it];
        }
        __syncthreads();

        if (ck + 1 < NCH) {
            #pragma unroll
            for (int it = 0; it < 7; it++)
                pre[it] = sa[it] ? *(const int4*)(sa[it] + (ck + 1) * 32) : zero4;
        }

        const ushort* wp0 = wT + (size_t)(ocw + l) * CPAD + ck * 32 + q * 8;
        #pragma unroll 1
        for (int g9 = 0; g9 < 9; g9++) {         // (dz,dy) group
            const int dz = g9 / 3, dy = g9 - dz * 3;
            const ushort* wpg = wp0 + (size_t)(g9 * 3) * (128 * CPAD);
            short8 A[3][4];
            #pragma unroll
            for (int dx = 0; dx < 3; dx++) {
                const ushort* wp = wpg + (size_t)dx * (128 * CPAD);
                A[dx][0] = *(const short8*)(wp);
                A[dx][1] = *(const short8*)(wp + 16 * CPAD);
                A[dx][2] = *(const short8*)(wp + 32 * CPAD);
                A[dx][3] = *(const short8*)(wp + 48 * CPAD);
            }
            const int pbase = ((mzw + dz) * 108 + dy * 18 + l) * 40 + q * 8;
            #pragma unroll
            for (int dx = 0; dx < 3; dx++) {
                #pragma unroll
                for (int mt = 0; mt < 4; mt++) {
                    const short8 b = *(const short8*)(&win[pbase + dx * 40 + mt * 720]);
                    acc[0][mt] = __builtin_amdgcn_mfma_f32_16x16x32_bf16(A[dx][0], b, acc[0][mt], 0, 0, 0);
                    acc[1][mt] = __builtin_amdgcn_mfma_f32_16x16x32_bf16(A[dx][1], b, acc[1][mt], 0, 0, 0);
                    acc[2][mt] = __builtin_amdgcn_mfma_f32_16x16x32_bf16(A[dx][2], b, acc[2][mt], 0, 0, 0);
                    acc[3][mt] = __builtin_amdgcn_mfma_f32_16x16x32_bf16(A[dx][3], b, acc[3][mt], 0, 0, 0);
                }
            }
        }
    }

    #pragma unroll
    for (int nt = 0; nt < 4; nt++) {
        const int ocb = ocw + nt * 16 + q * 4;
        const float4 bv = *(const float4*)(bias + ocb);
        #pragma unroll
        for (int mt = 0; mt < 4; mt++) {
            const int v = (z0 + mzw) * 2304 + (y0 + mt) * 48 + x0 + l;
            out[(size_t)(ocb + 0) * VOL + v] = acc[nt][mt][0] + bv.x;
            out[(size_t)(ocb + 1) * VOL + v] = acc[nt][mt][1] + bv.y;
            out[(size_t)(ocb + 2) * VOL + v] = acc[nt][mt][2] + bv.z;
            out[(size_t)(ocb + 3) * VOL + v] = acc[nt][mt][3] + bv.w;
        }
    }
}

// ---------------------------------------------------------------------------
// Two-phase per-channel stats. Phase 1: grid (128, 8) partial sums.
__global__ __launch_bounds__(256) void chan_stats_part_kernel(
    const float* __restrict__ x, float* __restrict__ pstats /* [128][8][2] */)
{
    const int c = blockIdx.x, g = blockIdx.y;
    const float4* p = (const float4*)(x + (size_t)c * VOL) + g * 3456;
    float s = 0.f, s2 = 0.f;
    #pragma unroll
    for (int j = 0; j < 14; j++) {
        const int i = threadIdx.x + j * 256;
        if (i < 3456) {
            const float4 v = p[i];
            s += v.x + v.y + v.z + v.w;
            s2 = fmaf(v.x, v.x, fmaf(v.y, v.y, fmaf(v.z, v.z, fmaf(v.w, v.w, s2))));
        }
    }
    s  += __shfl_down(s, 32);  s  += __shfl_down(s, 16);
    s  += __shfl_down(s, 8);   s  += __shfl_down(s, 4);
    s  += __shfl_down(s, 2);   s  += __shfl_down(s, 1);
    s2 += __shfl_down(s2, 32); s2 += __shfl_down(s2, 16);
    s2 += __shfl_down(s2, 8);  s2 += __shfl_down(s2, 4);
    s2 += __shfl_down(s2, 2);  s2 += __shfl_down(s2, 1);
    __shared__ float rs[4], rs2[4];
    if ((threadIdx.x & 63) == 0) {
        rs[threadIdx.x >> 6] = s;
        rs2[threadIdx.x >> 6] = s2;
    }
    __syncthreads();
    if (threadIdx.x == 0) {
        pstats[(c * 8 + g) * 2]     = rs[0] + rs[1] + rs[2] + rs[3];
        pstats[(c * 8 + g) * 2 + 1] = rs2[0] + rs2[1] + rs2[2] + rs2[3];
    }
}

// Phase 2: 1 block, 128 threads -> mean/rstd.
__global__ __launch_bounds__(128) void chan_stats_fin_kernel(
    const float* __restrict__ pstats, float* __restrict__ stats /* [128][2] */)
{
    const int c = threadIdx.x;
    float s = 0.f, s2 = 0.f;
    #pragma unroll
    for (int g = 0; g < 8; g++) {
        s  += pstats[(c * 8 + g) * 2];
        s2 += pstats[(c * 8 + g) * 2 + 1];
    }
    const float mean = s / (float)VOL;
    const float var  = s2 / (float)VOL - mean * mean;
    stats[c * 2]     = mean;
    stats[c * 2 + 1] = rsqrtf(var + 1e-5f);
}

__device__ __forceinline__ float gelu_exact(float h)
{
    return 0.5f * h * (1.f + erff(h * 0.70710678118654752f));
}

// Elementwise instance-norm apply + exact GELU (final output, fp32).
__global__ __launch_bounds__(256) void norm_gelu_kernel(
    const float* __restrict__ x, const float* __restrict__ stats,
    float* __restrict__ out)
{
    const size_t i = (size_t)blockIdx.x * 256 + threadIdx.x;  // float4 index
    const int c = (int)(i / (VOL / 4));
    const float mean = stats[c * 2], rstd = stats[c * 2 + 1];
    const float4 xv = ((const float4*)x)[i];
    float4 o;
    o.x = gelu_exact((xv.x - mean) * rstd);
    o.y = gelu_exact((xv.y - mean) * rstd);
    o.z = gelu_exact((xv.z - mean) * rstd);
    o.w = gelu_exact((xv.w - mean) * rstd);
    ((float4*)out)[i] = o;
}

// ---------------------------------------------------------------------------
// Fused: instance-norm apply + GELU + transpose [128][VOL] fp32 -> [VOL][128]
// bf16 (32x32 LDS tiles).
__global__ __launch_bounds__(256) void norm_gelu_transpose_kernel(
    const float* __restrict__ x, const float* __restrict__ stats,
    ushort* __restrict__ outT)
{
    __shared__ float tile[32][33];
    const int v0 = blockIdx.x * 32;
    const int c0 = blockIdx.y * 32;
    const int t = threadIdx.x;
    const int vl = t & 31, cl = t >> 5;
    #pragma unroll
    for (int i = 0; i < 4; i++) {
        const int c = c0 + cl + i * 8;
        const float mean = stats[c * 2], rstd = stats[c * 2 + 1];
        const float val = x[(size_t)c * VOL + v0 + vl];
        tile[cl + i * 8][vl] = gelu_exact((val - mean) * rstd);
    }
    __syncthreads();
    const int vw = t >> 3, cg = t & 7;
    ushort4 o;
    o.x = f2bf(tile[cg * 4 + 0][vw]);
    o.y = f2bf(tile[cg * 4 + 1][vw]);
    o.z = f2bf(tile[cg * 4 + 2][vw]);
    o.w = f2bf(tile[cg * 4 + 3][vw]);
    *(ushort4*)(outT + (size_t)(v0 + vw) * 128 + c0 + cg * 4) = o;
}

// ---------------------------------------------------------------------------
extern "C" void kernel_launch(void* const* d_in, const int* in_sizes, int n_in,
                              void* d_out, int out_size, void* d_ws, size_t ws_size,
                              hipStream_t stream)
{
    const float* src = (const float*)d_in[0];
    const float* tgt = (const float*)d_in[1];
    const float* psw = (const float*)d_in[2];
    const float* psb = (const float*)d_in[3];
    const float* ptw = (const float*)d_in[4];
    const float* ptb = (const float*)d_in[5];
    const float* e1w = (const float*)d_in[6];
    const float* e1b = (const float*)d_in[7];
    const float* e2w = (const float*)d_in[8];
    const float* e2b = (const float*)d_in[9];

    float* ws = (float*)d_ws;
    // Workspace (float-unit offsets; V = VOL):
    //   sp/tp fp16 [0,64V)        dead after corr -> h1 (fp32) reuses [0,128V)
    //   featT bf16 [128V,304V)    dead after conv1 -> h2 reuses [128V,256V)
    //   h1T bf16 [304V,368V)
    //   w1T bf16 [368V..), w2T, stats, pstats
    _Float16* sp  = (_Float16*)ws;
    _Float16* tp  = (_Float16*)(ws + (size_t)32 * VOL);
    ushort* featT = (ushort*)(ws + (size_t)128 * VOL);
    float*  h1    = ws;
    float*  h2    = ws + (size_t)128 * VOL;
    ushort* h1T   = (ushort*)(ws + (size_t)304 * VOL);
    float*  w1Tf  = ws + (size_t)368 * VOL;
    ushort* w1T   = (ushort*)w1Tf;
    float*  w2Tf  = w1Tf + 608256;           // 27*128*352 ushorts
    ushort* w2T   = (ushort*)w2Tf;
    float*  stats = w2Tf + 221184;           // 27*128*128 ushorts
    float*  pstats = stats + 256;            // 128*8*2 floats

    wprep_kernel<346, 352><<<128, 256, 0, stream>>>(e1w, w1T);
    wprep_kernel<128, 128><<<128, 256, 0, stream>>>(e2w, w2T);

    proj_l2norm_kernel<<<432, 256, 0, stream>>>(src, psw, psb, sp);
    proj_l2norm_kernel<<<432, 256, 0, stream>>>(tgt, ptw, ptb, tp);
    corr_fused_kernel<<<3456, 256, 0, stream>>>(sp, tp, featT);

    conv3_mfma_kernel<352><<<864, 256, 0, stream>>>(featT, w1T, e1b, h1);
    chan_stats_part_kernel<<<dim3(128, 8), 256, 0, stream>>>(h1, pstats);
    chan_stats_fin_kernel<<<1, 128, 0, stream>>>(pstats, stats);
    norm_gelu_transpose_kernel<<<dim3(3456, 4), 256, 0, stream>>>(h1, stats, h1T);

    conv3_mfma_kernel<128><<<864, 256, 0, stream>>>(h1T, w2T, e2b, h2);
    chan_stats_part_kernel<<<dim3(128, 8), 256, 0, stream>>>(h2, pstats);
    chan_stats_fin_kernel<<<1, 128, 0, stream>>>(pstats, stats);
    norm_gelu_kernel<<<(128 * VOL) / 1024, 256, 0, stream>>>(h2, stats, (float*)d_out);
}